// Round 4
// baseline (356.256 us; speedup 1.0000x reference)
//
#include <hip/hip_runtime.h>

// out[b,o] = x[b,:] @ W_lin[:,o] + x[b] @ W_nl[o] @ x[b]
// GEMM out = z @ Wz, z[b,32i+j] = x[b,i]*x[b,j], K=1024 (+ linear as a 33rd
// k-step), via v_mfma_f32_16x16x32_f16.
//
// R4: one wave owns FULL N=32 (4 acc chains) over a PAIR of 16-row tiles, so
// each LDS B-fragment read feeds 4 MFMAs and A-products are computed once
// (R2/R3 duplicated them per n-half wave). B = f16(16*W) in fragment order in
// 66 KiB LDS (shared per block; W_lin folded in as ks==32). Products via
// packed f32 mul + v_cvt_pkrtz. No barriers in the main loop, no reductions.
// Register budget ~125 <= 128 -> launch_bounds(512,4): 16 waves/CU.

typedef __attribute__((ext_vector_type(8))) _Float16 f16x8;
typedef __attribute__((ext_vector_type(4))) _Float16 f16x4;
typedef __attribute__((ext_vector_type(2))) _Float16 f16x2;
typedef __attribute__((ext_vector_type(4))) float floatx4;

#define NB       524288
#define NTILES   (NB / 16)          // 32768
#define NBLK     512
#define NSTREAMS (NBLK * 8)         // 4096 waves, full-N each
#define TPW      (NTILES / NSTREAMS) // 8 tiles per wave = 4 pairs

static __device__ inline f16x2 cvt2(float a, float b) {
    auto t = __builtin_amdgcn_cvt_pkrtz(a, b);
    return __builtin_bit_cast(f16x2, t);
}

// af[j] = f16(s * w[j]), j in [0,8): packed muls + packed cvt
static __device__ inline f16x8 mk_af(float s, floatx4 w0, floatx4 w1) {
    f16x2 a = cvt2(s * w0[0], s * w0[1]);
    f16x2 b = cvt2(s * w0[2], s * w0[3]);
    f16x2 c = cvt2(s * w1[0], s * w1[1]);
    f16x2 d = cvt2(s * w1[2], s * w1[3]);
    f16x4 lo = __builtin_shufflevector(a, b, 0, 1, 2, 3);
    f16x4 hi = __builtin_shufflevector(c, d, 0, 1, 2, 3);
    return __builtin_shufflevector(lo, hi, 0, 1, 2, 3, 4, 5, 6, 7);
}

__global__ __launch_bounds__(512, 4)
void nnode_kernel(const float* __restrict__ x, const float* __restrict__ Wlin,
                  const float* __restrict__ Wnl, float* __restrict__ out) {
    // [nh][ks 0..32][lane] : frag element j = f16(16 * Wz[k=q*8+j][o=col+16nh])
    __shared__ f16x8 wlds[2 * 33 * 64];   // 66 KiB

    const int tid = threadIdx.x;

    // ---- stage 16*W into LDS in MFMA B-fragment order (one-time) ----
    for (int r2 = tid; r2 < 33 * 64; r2 += 512) {
        const int ks = r2 >> 6;
        const int ln = r2 & 63;
        const int qq = ln >> 4;
        #pragma unroll
        for (int nh = 0; nh < 2; ++nh) {
            const int o = (ln & 15) + 16 * nh;
            f16x8 v;
            if (ks < 32) {
                const float* src = Wnl + (size_t)o * 1024 + ks * 32 + qq * 8;
                floatx4 a = *(const floatx4*)(src);
                floatx4 b = *(const floatx4*)(src + 4);
                v = mk_af(16.0f, a, b);
            } else {
                floatx4 a, b;
                #pragma unroll
                for (int j = 0; j < 4; ++j) {
                    a[j] = Wlin[(qq * 8 + j) * 32 + o];
                    b[j] = Wlin[(qq * 8 + 4 + j) * 32 + o];
                }
                v = mk_af(16.0f, a, b);
            }
            wlds[nh * (33 * 64) + r2] = v;
        }
    }
    __syncthreads();

    const int wave = tid >> 6;
    const int lane = tid & 63;
    const int q    = lane >> 4;   // quad: A k-window / C row group
    const int col  = lane & 15;   // A row / C column

    const int stream = blockIdx.x * 8 + wave;

    #pragma unroll 1
    for (int p = 0; p < TPW / 2; ++p) {
        const int tA = stream * TPW + 2 * p;
        const int tB = tA + 1;

        const float* xra = x + (size_t)(tA * 16 + col) * 32;
        const float* xrb = x + (size_t)(tB * 16 + col) * 32;

        floatx4 xa[8], xb[8];
        #pragma unroll
        for (int c = 0; c < 8; ++c) xa[c] = *(const floatx4*)(xra + c * 4);
        #pragma unroll
        for (int c = 0; c < 8; ++c) xb[c] = *(const floatx4*)(xrb + c * 4);
        floatx4 wa0 = *(const floatx4*)(xra + q * 8);
        floatx4 wa1 = *(const floatx4*)(xra + q * 8 + 4);
        floatx4 wb0 = *(const floatx4*)(xrb + q * 8);
        floatx4 wb1 = *(const floatx4*)(xrb + q * 8 + 4);

        floatx4 aA0 = {0.f,0.f,0.f,0.f}, aA1 = {0.f,0.f,0.f,0.f};
        floatx4 aB0 = {0.f,0.f,0.f,0.f}, aB1 = {0.f,0.f,0.f,0.f};

        #pragma unroll
        for (int ks = 0; ks < 33; ++ks) {
            f16x8 bf0 = wlds[ks * 64 + lane];
            f16x8 bf1 = wlds[33 * 64 + ks * 64 + lane];
            const float sA = (ks < 32) ? xa[ks >> 2][ks & 3] : 1.0f;
            const float sB = (ks < 32) ? xb[ks >> 2][ks & 3] : 1.0f;
            f16x8 afA = mk_af(sA, wa0, wa1);
            f16x8 afB = mk_af(sB, wb0, wb1);
            aA0 = __builtin_amdgcn_mfma_f32_16x16x32_f16(afA, bf0, aA0, 0, 0, 0);
            aA1 = __builtin_amdgcn_mfma_f32_16x16x32_f16(afA, bf1, aA1, 0, 0, 0);
            aB0 = __builtin_amdgcn_mfma_f32_16x16x32_f16(afB, bf0, aB0, 0, 0, 0);
            aB1 = __builtin_amdgcn_mfma_f32_16x16x32_f16(afB, bf1, aB1, 0, 0, 0);
        }

        // C/D: row = q*4 + r, col = col (+16); undo the *16 weight scale
        float* oA = out + (size_t)(tA * 16 + q * 4) * 32 + col;
        float* oB = out + (size_t)(tB * 16 + q * 4) * 32 + col;
        #pragma unroll
        for (int r = 0; r < 4; ++r) {
            oA[(size_t)r * 32]      = aA0[r] * 0.0625f;
            oA[(size_t)r * 32 + 16] = aA1[r] * 0.0625f;
            oB[(size_t)r * 32]      = aB0[r] * 0.0625f;
            oB[(size_t)r * 32 + 16] = aB1[r] * 0.0625f;
        }
    }
}

extern "C" void kernel_launch(void* const* d_in, const int* in_sizes, int n_in,
                              void* d_out, int out_size, void* d_ws, size_t ws_size,
                              hipStream_t stream) {
    const float* x    = (const float*)d_in[0];
    const float* Wlin = (const float*)d_in[1];
    const float* Wnl  = (const float*)d_in[2];
    float* out        = (float*)d_out;
    nnode_kernel<<<dim3(NBLK), dim3(512), 0, stream>>>(x, Wlin, Wnl, out);
}

// Round 5
// 223.233 us; speedup vs baseline: 1.5959x; 1.5959x over previous
//
#include <hip/hip_runtime.h>

// out[b,o] = x[b,:] @ W_lin[:,o] + x[b] @ W_nl[o] @ x[b]
// GEMM out = z @ Wz, z[b, 32i+j] = x[b,i]*x[b,j] (K=1024) + W_lin as two
// extra K=16 steps (steps 66,67). Computed with v_mfma_f32_32x32x16_bf16:
// one wave owns a 32-row tile x full N=32 -> ONE acc chain (16 regs), ONE
// ds_read_b128 B-fragment per k-step.
//
// Layouts (32x32x16): A[m = lane&31][k = (lane>>5)*8 + j]
//                     B[k = (lane>>5)*8 + j][n = lane&31]
//                     C/D col = lane&31, row = (reg&3) + 8*(reg>>2) + 4*(lane>>5)
// A-frag synthesis: global k = step*16 + half*8 + j maps to (i = step>>1,
// j' = (step&1)*16 + half*8 + j), so af[j] = x[m, step>>1] * x[m, j'].
//
// Sizing (the R2-R4 lesson): regs ~95 (row 32 + windows 16 + acc 16 + temps)
// -> no spill, 4 waves/SIMD; LDS 68 KiB -> 2 blocks/CU; launch_bounds(512)
// with NO second arg (the second arg caused R4's 64-VGPR spill disaster).
// No barriers in the main loop.

typedef __attribute__((ext_vector_type(8)))  __bf16 bf16x8;
typedef __attribute__((ext_vector_type(4)))  float  floatx4;
typedef __attribute__((ext_vector_type(16))) float  floatx16;

#define NB    524288
#define NT    (NB / 32)       // 16384 32-row tiles
#define NBLK  512
#define NSTR  (NBLK * 8)      // 4096 wave streams
#define TPW   (NT / NSTR)     // 4 tiles per wave

__global__ __launch_bounds__(512)
void nnode_kernel(const float* __restrict__ x, const float* __restrict__ Wlin,
                  const float* __restrict__ Wnl, float* __restrict__ out) {
    __shared__ bf16x8 wlds[68 * 64];   // 68 KiB, B-fragments in MFMA order

    const int tid = threadIdx.x;

    // ---- one-time staging of Wz into fragment order ----
    for (int r = tid; r < 68 * 64; r += 512) {
        const int step = r >> 6;        // wave-uniform (r&63 == lane)
        const int ln   = r & 63;
        const int o    = ln & 31;
        const int hf   = ln >> 5;
        bf16x8 v;
        if (step < 66) {
            const int i  = step >> 1;
            const int jb = (step & 1) * 16 + hf * 8;
            const float* src = Wnl + (size_t)o * 1024 + i * 32 + jb;
            floatx4 a = *(const floatx4*)(src);
            floatx4 b = *(const floatx4*)(src + 4);
            #pragma unroll
            for (int j = 0; j < 4; ++j) { v[j] = (__bf16)a[j]; v[j + 4] = (__bf16)b[j]; }
        } else {
            const int kb = (step - 66) * 16 + hf * 8;
            #pragma unroll
            for (int j = 0; j < 8; ++j) v[j] = (__bf16)Wlin[(size_t)(kb + j) * 32 + o];
        }
        wlds[r] = v;
    }
    __syncthreads();

    const int wave = tid >> 6;
    const int lane = tid & 63;
    const int half = lane >> 5;
    const int m    = lane & 31;     // A row within tile; also C/D col (=o)

    const int stream = blockIdx.x * 8 + wave;

    #pragma unroll 1
    for (int t = 0; t < TPW; ++t) {
        const int tile = stream * TPW + t;
        const float* xr = x + ((size_t)tile * 32 + m) * 32;

        floatx4 xv[8];                          // full row: scalars s_i
        #pragma unroll
        for (int c = 0; c < 8; ++c) xv[c] = *(const floatx4*)(xr + c * 4);
        // windows: even steps use x[m, half*8..+8), odd use x[m, 16+half*8..+8)
        floatx4 e0 = *(const floatx4*)(xr + half * 8);
        floatx4 e1 = *(const floatx4*)(xr + half * 8 + 4);
        floatx4 q0 = *(const floatx4*)(xr + 16 + half * 8);
        floatx4 q1 = *(const floatx4*)(xr + 16 + half * 8 + 4);

        floatx16 acc;
        #pragma unroll
        for (int r = 0; r < 16; ++r) acc[r] = 0.0f;

        #pragma unroll
        for (int i = 0; i < 32; ++i) {
            const float s = xv[i >> 2][i & 3];   // static after unroll
            bf16x8 afe, afo;
            #pragma unroll
            for (int j = 0; j < 4; ++j) {
                afe[j]     = (__bf16)(s * e0[j]);
                afe[j + 4] = (__bf16)(s * e1[j]);
                afo[j]     = (__bf16)(s * q0[j]);
                afo[j + 4] = (__bf16)(s * q1[j]);
            }
            bf16x8 bf0 = wlds[(2 * i) * 64 + lane];
            bf16x8 bf1 = wlds[(2 * i + 1) * 64 + lane];
            acc = __builtin_amdgcn_mfma_f32_32x32x16_bf16(afe, bf0, acc, 0, 0, 0);
            acc = __builtin_amdgcn_mfma_f32_32x32x16_bf16(afo, bf1, acc, 0, 0, 0);
        }
        // linear part: A element = x[m, k] itself
        {
            bf16x8 afe, afo;
            #pragma unroll
            for (int j = 0; j < 4; ++j) {
                afe[j] = (__bf16)e0[j]; afe[j + 4] = (__bf16)e1[j];
                afo[j] = (__bf16)q0[j]; afo[j + 4] = (__bf16)q1[j];
            }
            acc = __builtin_amdgcn_mfma_f32_32x32x16_bf16(afe, wlds[66 * 64 + lane], acc, 0, 0, 0);
            acc = __builtin_amdgcn_mfma_f32_32x32x16_bf16(afo, wlds[67 * 64 + lane], acc, 0, 0, 0);
        }

        // store: out[tile*32 + row_r, o = m], row_r = (r&3) + 8*(r>>2) + 4*half
        float* ob = out + ((size_t)tile * 32 + 4 * half) * 32 + m;
        #pragma unroll
        for (int r = 0; r < 16; ++r) {
            const int rowr = (r & 3) + 8 * (r >> 2);
            ob[(size_t)rowr * 32] = acc[r];
        }
    }
}

extern "C" void kernel_launch(void* const* d_in, const int* in_sizes, int n_in,
                              void* d_out, int out_size, void* d_ws, size_t ws_size,
                              hipStream_t stream) {
    const float* x    = (const float*)d_in[0];
    const float* Wlin = (const float*)d_in[1];
    const float* Wnl  = (const float*)d_in[2];
    float* out        = (float*)d_out;
    nnode_kernel<<<dim3(NBLK), dim3(512), 0, stream>>>(x, Wlin, Wnl, out);
}